// Round 12
// baseline (72.790 us; speedup 1.0000x reference)
//
#include <hip/hip_runtime.h>

#define NB 512
#define SLOTS 32
#define D 1024
#define D4 256           // float4 per row
#define CAP 64
#define TAU_INV 10.0f
#define BT 512           // 8 waves

// ---- kernel 0: zero per-bucket counters ----
__global__ void k_zero(int* __restrict__ cnt) {
    if (threadIdx.x < NB) cnt[threadIdx.x] = 0;
}

// ---- kernel 1: per-bucket token lists (order nondeterministic; per-token
//      math is list-order-invariant → deterministic output) ----
__global__ void k_build(const int* __restrict__ tids, int n,
                        int* __restrict__ cnt, int* __restrict__ list) {
    int i = blockIdx.x * 256 + threadIdx.x;
    if (i < n) {
        int b = tids[i] & (NB - 1);
        int p = atomicAdd(&cnt[b], 1);
        if (p < CAP) list[b * CAP + p] = i;
    }
}

// ---- kernel 2: WAVE-AUTONOMOUS, barrier-free, zero-LDS.
//      block = (bucket, parity); wave w owns tokens w, w+8, ... of its part
//      (mean 1 token/wave → balance; early-exit waves free slots → elastic).
//      4-row load groups in unroll-1 loops: 16 loads in flight, short live
//      ranges (anti-spill, per R11 remat evidence). In-wave softmax with
//      permuted slot mapping (paired-halving reduce, R10-verified).
__global__ __launch_bounds__(BT, 2)
void k_main(const float* __restrict__ query,    // [NT][D]
            const int*   __restrict__ tids,     // [NT]
            const float* __restrict__ skeys,    // [NB*SLOTS][D]
            const float* __restrict__ svals,    // [NB*SLOTS][D]
            const int*   __restrict__ stids,    // [NB*SLOTS]
            const float* __restrict__ centroid, // [NB][D]
            float*       __restrict__ out,      // [NT][D]
            const int*   __restrict__ cnt,
            const int*   __restrict__ list)
{
    const int bucket = blockIdx.x & (NB - 1);   // parts share XCD (512%8==0)
    const int part   = blockIdx.x >> 9;         // 0/1
    const int lane   = threadIdx.x & 63;
    const int wid    = threadIdx.x >> 6;        // 0..7

    const int count = min(cnt[bucket], CAP);
    const int ncnt  = (count - part + 1) >> 1;  // tokens owned by this part
    if (ncnt <= 0) return;

    // permuted slot for this lane: after the paired-halving reduce, lane l
    // holds slot (l&~3) | perm(l&3), perm = {0,2,1,3}
    const int ls      = lane & 31;
    const int my_slot = (ls & ~3) | (((ls & 1) << 1) | ((ls >> 1) & 1));
    const int my_stid = stids[bucket * SLOTS + my_slot];

    const float4* kb = (const float4*)(skeys + (size_t)bucket * SLOTS * D);
    const float4* vb = (const float4*)(svals + (size_t)bucket * SLOTS * D);
    const float4* cb = (const float4*)(centroid + (size_t)bucket * D);

    float4 anc[4];
    #pragma unroll
    for (int j = 0; j < 4; ++j) anc[j] = cb[lane + 64 * j];

    for (int t = wid; t < ncnt; t += 8) {
        const int tok    = list[bucket * CAP + part + 2 * t];
        const int my_tid = tids[tok];            // uniform → s-broadcast

        // ---- unified query in registers ----
        float4 uq[4];
        {
            const float4* q4 = (const float4*)(query + (size_t)tok * D);
            float4 qv[4];
            float ss = 0.f;
            #pragma unroll
            for (int j = 0; j < 4; ++j) {
                qv[j] = q4[lane + 64 * j];
                ss += qv[j].x*qv[j].x + qv[j].y*qv[j].y + qv[j].z*qv[j].z + qv[j].w*qv[j].w;
            }
            #pragma unroll
            for (int off = 32; off >= 1; off >>= 1) ss += __shfl_xor(ss, off);
            const float qn = 0.5f / fmaxf(sqrtf(ss), 1e-12f);   // folds ALPHA=0.5
            float ss2 = 0.f;
            #pragma unroll
            for (int j = 0; j < 4; ++j) {
                uq[j].x = qv[j].x * qn + 0.5f * anc[j].x;
                uq[j].y = qv[j].y * qn + 0.5f * anc[j].y;
                uq[j].z = qv[j].z * qn + 0.5f * anc[j].z;
                uq[j].w = qv[j].w * qn + 0.5f * anc[j].w;
                ss2 += uq[j].x*uq[j].x + uq[j].y*uq[j].y + uq[j].z*uq[j].z + uq[j].w*uq[j].w;
            }
            #pragma unroll
            for (int off = 32; off >= 1; off >>= 1) ss2 += __shfl_xor(ss2, off);
            const float un = 1.0f / fmaxf(sqrtf(ss2), 1e-12f);
            #pragma unroll
            for (int j = 0; j < 4; ++j) {
                uq[j].x *= un; uq[j].y *= un; uq[j].z *= un; uq[j].w *= un;
            }
        }

        // ---- scores: 8 groups of 4 rows; lane keeps its permuted slot ----
        float sc = 0.f;
        #pragma unroll 1
        for (int g = 0; g < 8; ++g) {
            const float4* kr = kb + (size_t)(g * 4) * D4;
            float4 k0[4], k1[4], k2[4], k3[4];
            #pragma unroll
            for (int j = 0; j < 4; ++j) {
                k0[j] = kr[0 * D4 + lane + 64 * j];
                k1[j] = kr[1 * D4 + lane + 64 * j];
                k2[j] = kr[2 * D4 + lane + 64 * j];
                k3[j] = kr[3 * D4 + lane + 64 * j];
            }
            float P0 = 0.f, P1 = 0.f, P2 = 0.f, P3 = 0.f;
            #pragma unroll
            for (int j = 0; j < 4; ++j) {
                const float4 u = uq[j];
                P0 += k0[j].x*u.x + k0[j].y*u.y + k0[j].z*u.z + k0[j].w*u.w;
                P1 += k1[j].x*u.x + k1[j].y*u.y + k1[j].z*u.z + k1[j].w*u.w;
                P2 += k2[j].x*u.x + k2[j].y*u.y + k2[j].z*u.z + k2[j].w*u.w;
                P3 += k3[j].x*u.x + k3[j].y*u.y + k3[j].z*u.z + k3[j].w*u.w;
            }
            // paired-halving reduce: 7 shfl; result replicated to all lanes,
            // lane l holds slot 4g + perm(l&3)   (R10-verified)
            {
                const bool hi = (lane & 1) != 0;
                const float sA = hi ? P0 : P2, kA = hi ? P2 : P0;
                P0 = kA + __shfl_xor(sA, 1);
                const float sB = hi ? P1 : P3, kB = hi ? P3 : P1;
                P1 = kB + __shfl_xor(sB, 1);
            }
            {
                const bool hi = (lane & 2) != 0;
                const float sA = hi ? P0 : P1, kA = hi ? P1 : P0;
                P0 = kA + __shfl_xor(sA, 2);
            }
            P0 += __shfl_xor(P0, 4);
            P0 += __shfl_xor(P0, 8);
            P0 += __shfl_xor(P0, 16);
            P0 += __shfl_xor(P0, 32);
            if ((ls >> 2) == g) sc = P0;
        }

        // ---- in-wave softmax + hard-match over permuted slots ----
        float p;
        {
            float m = sc;
            #pragma unroll
            for (int off = 16; off >= 1; off >>= 1) m = fmaxf(m, __shfl_xor(m, off));
            const float e = __expf((sc - m) * TAU_INV);
            const float f = (my_stid == my_tid) ? 1.f : 0.f;
            float es = e, ms = f;
            #pragma unroll
            for (int off = 16; off >= 1; off >>= 1) {
                es += __shfl_xor(es, off);
                ms += __shfl_xor(ms, off);
            }
            p = (ms > 0.f) ? f / (ms + 1e-9f) : e / es;
        }

        // ---- values: 8 groups of 4 rows; weights via permuted shfl ----
        float4 acc[4];
        #pragma unroll
        for (int j = 0; j < 4; ++j) acc[j] = make_float4(0.f, 0.f, 0.f, 0.f);
        #pragma unroll 1
        for (int g = 0; g < 8; ++g) {
            const float4* vr = vb + (size_t)(g * 4) * D4;
            float4 r0[4], r1[4], r2[4], r3[4];
            #pragma unroll
            for (int j = 0; j < 4; ++j) {
                r0[j] = vr[0 * D4 + lane + 64 * j];
                r1[j] = vr[1 * D4 + lane + 64 * j];
                r2[j] = vr[2 * D4 + lane + 64 * j];
                r3[j] = vr[3 * D4 + lane + 64 * j];
            }
            // weight of slot 4g+r lives in lane 4g+perm(r), perm={0,2,1,3}
            const float ws0 = __shfl(p, g * 4 + 0);
            const float ws1 = __shfl(p, g * 4 + 2);
            const float ws2 = __shfl(p, g * 4 + 1);
            const float ws3 = __shfl(p, g * 4 + 3);
            #pragma unroll
            for (int j = 0; j < 4; ++j) {
                acc[j].x += ws0*r0[j].x + ws1*r1[j].x + ws2*r2[j].x + ws3*r3[j].x;
                acc[j].y += ws0*r0[j].y + ws1*r1[j].y + ws2*r2[j].y + ws3*r3[j].y;
                acc[j].z += ws0*r0[j].z + ws1*r1[j].z + ws2*r2[j].z + ws3*r3[j].z;
                acc[j].w += ws0*r0[j].w + ws1*r1[j].w + ws2*r2[j].w + ws3*r3[j].w;
            }
        }

        float4* o4 = (float4*)(out + (size_t)tok * D);
        #pragma unroll
        for (int j = 0; j < 4; ++j) o4[lane + 64 * j] = acc[j];
    }
}

extern "C" void kernel_launch(void* const* d_in, const int* in_sizes, int n_in,
                              void* d_out, int out_size, void* d_ws, size_t ws_size,
                              hipStream_t stream) {
    const float* query    = (const float*)d_in[0];
    const int*   tids     = (const int*)  d_in[1];
    const float* skeys    = (const float*)d_in[2];
    const float* svals    = (const float*)d_in[3];
    const int*   stids    = (const int*)  d_in[4];
    const float* centroid = (const float*)d_in[5];
    float* out = (float*)d_out;
    const int n_tokens = in_sizes[1];

    int* cnt  = (int*)d_ws;             // [NB]
    int* list = cnt + NB;               // [NB*CAP]

    k_zero<<<1, 512, 0, stream>>>(cnt);
    k_build<<<(n_tokens + 255) / 256, 256, 0, stream>>>(tids, n_tokens, cnt, list);
    k_main<<<NB * 2, BT, 0, stream>>>(query, tids, skeys, svals, stids,
                                      centroid, out, cnt, list);
}

// Round 13
// 60.466 us; speedup vs baseline: 1.2038x; 1.2038x over previous
//
#include <hip/hip_runtime.h>

#define NB 512
#define SLOTS 32
#define D 1024
#define D4 256           // D/4 (float4 per row)
#define TC 8             // tokens per chunk
#define CAP 64           // list capacity per bucket
#define TAU_INV 10.0f
#define BT 256           // threads per block (4 waves)

// ---- kernel 0: zero the per-bucket counters ----
__global__ void k_zero(int* __restrict__ cnt) {
    if (threadIdx.x < NB) cnt[threadIdx.x] = 0;
}

// ---- kernel 1: build per-bucket token lists (order nondeterministic, but
//      per-token math is order-invariant → deterministic output) ----
__global__ void k_build(const int* __restrict__ tids, int n,
                        int* __restrict__ cnt, int* __restrict__ list) {
    int i = blockIdx.x * 256 + threadIdx.x;
    if (i < n) {
        int b = tids[i] & (NB - 1);
        int p = atomicAdd(&cnt[b], 1);
        if (p < CAP) list[b * CAP + p] = i;
    }
}

// ---- kernel 2: R11 structure + straggler elimination.
//      grid = 3*NB. blocks [0,NB): OVERFLOW — handle list positions >= 16
//      (only ~2 buckets have any; the rest exit instantly; scheduled FIRST so
//      they overlap the primaries). blocks [NB,3NB): PRIMARY (bucket,parity)
//      — positions part, part+2, ... < 16, so ncnt <= 8: exactly one chunk.
//      R11 post-mortem: 1-2 straggler buckets with a 2nd chunk serialized
//      ~30us while 1022 blocks idled (occupancy 32% vs 50% static).
__global__ __launch_bounds__(BT, 2)
void k_main(const float* __restrict__ query,    // [NT][D]
            const int*   __restrict__ tids,     // [NT]
            const float* __restrict__ skeys,    // [NB*SLOTS][D]
            const float* __restrict__ svals,    // [NB*SLOTS][D]
            const int*   __restrict__ stids,    // [NB*SLOTS]
            const float* __restrict__ centroid, // [NB][D]
            float*       __restrict__ out,      // [NT][D]
            const int*   __restrict__ cnt,
            const int*   __restrict__ list)
{
    const int bid  = blockIdx.x;
    const int tidx = threadIdx.x;               // 0..255
    const int lane = tidx & 63;
    const int wid  = tidx >> 6;                 // 0..3

    int bucket, pos_base, pos_stride, ncnt;
    if (bid < NB) {                             // overflow block
        bucket = bid;
        const int count = min(cnt[bucket], CAP);
        ncnt = count - 16;                      // positions 16..count-1
        if (ncnt <= 0) return;
        pos_base = 16; pos_stride = 1;
    } else {                                    // primary block
        const int b2 = bid - NB;
        bucket = b2 & (NB - 1);                 // parts share XCD (512%8==0)
        const int part = b2 >> 9;               // 0/1
        const int c16 = min(min(cnt[bucket], CAP), 16);
        ncnt = (c16 - part + 1) >> 1;           // parity split of [0,16)
        if (ncnt <= 0) return;
        pos_base = part; pos_stride = 2;
    }

    __shared__ float s_uq[TC][D];               // 32 KB
    __shared__ float s_scores[TC][SLOTS];       // 1 KB
    __shared__ float s_probs[TC][SLOTS];        // 1 KB
    __shared__ int   s_tok[TC];
    __shared__ int   s_ttid[TC];

    const int slot_tid = stids[bucket * SLOTS + (lane & 31)];
    const float4* kb = (const float4*)(skeys + (size_t)bucket * SLOTS * D);
    const float4* vb = (const float4*)(svals + (size_t)bucket * SLOTS * D);
    const float4* cb = (const float4*)(centroid + (size_t)bucket * D);

    for (int c0 = 0; c0 < ncnt; c0 += TC) {
        const int nt = min(TC, ncnt - c0);

        // ---- query phase: wave w owns tokens w, w+4 (anchor from L2) ----
        for (int t = wid; t < nt; t += 4) {
            const int tok = list[bucket * CAP + pos_base + pos_stride * (c0 + t)];
            const float4* q4 = (const float4*)(query + (size_t)tok * D);
            float4 qv[4], anc[4];
            float ss = 0.f;
            #pragma unroll
            for (int j = 0; j < 4; ++j) {
                qv[j]  = q4[lane + 64 * j];
                anc[j] = cb[lane + 64 * j];
                ss += qv[j].x*qv[j].x + qv[j].y*qv[j].y + qv[j].z*qv[j].z + qv[j].w*qv[j].w;
            }
            #pragma unroll
            for (int off = 32; off >= 1; off >>= 1) ss += __shfl_xor(ss, off);
            const float qn = 0.5f / fmaxf(sqrtf(ss), 1e-12f);   // folds ALPHA=0.5
            float4 uv[4];
            float ss2 = 0.f;
            #pragma unroll
            for (int j = 0; j < 4; ++j) {
                uv[j].x = qv[j].x * qn + 0.5f * anc[j].x;
                uv[j].y = qv[j].y * qn + 0.5f * anc[j].y;
                uv[j].z = qv[j].z * qn + 0.5f * anc[j].z;
                uv[j].w = qv[j].w * qn + 0.5f * anc[j].w;
                ss2 += uv[j].x*uv[j].x + uv[j].y*uv[j].y + uv[j].z*uv[j].z + uv[j].w*uv[j].w;
            }
            #pragma unroll
            for (int off = 32; off >= 1; off >>= 1) ss2 += __shfl_xor(ss2, off);
            const float un = 1.0f / fmaxf(sqrtf(ss2), 1e-12f);
            #pragma unroll
            for (int j = 0; j < 4; ++j) {
                ((float4*)s_uq[t])[lane + 64 * j] =
                    make_float4(uv[j].x*un, uv[j].y*un, uv[j].z*un, uv[j].w*un);
            }
            if (lane == 0) { s_tok[t] = tok; s_ttid[t] = tids[tok]; }
        }
        __syncthreads();

        // ---- scores: 2 sequential rounds; wave owns 4 slots/round ----
        #pragma unroll 1
        for (int rnd = 0; rnd < 2; ++rnd) {
            const int sbase = rnd * 16 + wid * 4;
            const float4* kr = kb + (size_t)sbase * D4;
            float4 k0[4], k1[4], k2[4], k3[4];
            #pragma unroll
            for (int j = 0; j < 4; ++j) {
                k0[j] = kr[0 * D4 + lane + 64 * j];
                k1[j] = kr[1 * D4 + lane + 64 * j];
                k2[j] = kr[2 * D4 + lane + 64 * j];
                k3[j] = kr[3 * D4 + lane + 64 * j];
            }
            for (int t = 0; t < nt; ++t) {          // runtime bound: anti-spill
                const float4* u4 = (const float4*)s_uq[t];
                float P0 = 0.f, P1 = 0.f, P2 = 0.f, P3 = 0.f;
                #pragma unroll
                for (int j = 0; j < 4; ++j) {
                    float4 u = u4[lane + 64 * j];
                    P0 += k0[j].x*u.x + k0[j].y*u.y + k0[j].z*u.z + k0[j].w*u.w;
                    P1 += k1[j].x*u.x + k1[j].y*u.y + k1[j].z*u.z + k1[j].w*u.w;
                    P2 += k2[j].x*u.x + k2[j].y*u.y + k2[j].z*u.z + k2[j].w*u.w;
                    P3 += k3[j].x*u.x + k3[j].y*u.y + k3[j].z*u.z + k3[j].w*u.w;
                }
                // batched paired-halving reduce: 4 values, 7 shfl (R10-verified)
                {
                    const bool hi = (lane & 1) != 0;
                    const float sA = hi ? P0 : P2, kA = hi ? P2 : P0;
                    P0 = kA + __shfl_xor(sA, 1);
                    const float sB = hi ? P1 : P3, kB = hi ? P3 : P1;
                    P1 = kB + __shfl_xor(sB, 1);
                }
                {
                    const bool hi = (lane & 2) != 0;
                    const float sA = hi ? P0 : P1, kA = hi ? P1 : P0;
                    P0 = kA + __shfl_xor(sA, 2);
                }
                P0 += __shfl_xor(P0, 4);
                P0 += __shfl_xor(P0, 8);
                P0 += __shfl_xor(P0, 16);
                P0 += __shfl_xor(P0, 32);
                // lane l<4 holds slot id = ((l&1)<<1)|((l>>1)&1)
                if (lane < 4)
                    s_scores[t][sbase + (((lane & 1) << 1) | ((lane >> 1) & 1))] = P0;
            }
        }
        __syncthreads();

        // ---- softmax + hard-match: wave w owns tokens w, w+4; lanes 0..31 ----
        for (int t = wid; t < nt; t += 4) {
            if (lane < 32) {
                const float sc = s_scores[t][lane];
                float mx = sc;
                #pragma unroll
                for (int off = 16; off >= 1; off >>= 1) mx = fmaxf(mx, __shfl_xor(mx, off));
                const float e = __expf((sc - mx) * TAU_INV);
                const float f = (slot_tid == s_ttid[t]) ? 1.f : 0.f;
                float es = e, ms = f;
                #pragma unroll
                for (int off = 16; off >= 1; off >>= 1) {
                    es += __shfl_xor(es, off);
                    ms += __shfl_xor(ms, off);
                }
                s_probs[t][lane] = (ms > 0.f) ? f / (ms + 1e-9f) : e / es;
            }
        }
        __syncthreads();

        // ---- values: thread owns float4 column tidx; 4 rounds of 8 rows ----
        {
            float4 acc[TC];
            #pragma unroll
            for (int t = 0; t < TC; ++t) acc[t] = make_float4(0.f, 0.f, 0.f, 0.f);

            #pragma unroll 1
            for (int s0 = 0; s0 < SLOTS; s0 += 8) {
                float4 v[8];
                #pragma unroll
                for (int i = 0; i < 8; ++i) v[i] = vb[(s0 + i) * D4 + tidx];
                #pragma unroll
                for (int t = 0; t < TC; ++t) {
                    if (t < nt) {
                        const float4 pA = ((const float4*)s_probs[t])[(s0 >> 2) + 0];
                        const float4 pB = ((const float4*)s_probs[t])[(s0 >> 2) + 1];
                        acc[t].x += pA.x*v[0].x + pA.y*v[1].x + pA.z*v[2].x + pA.w*v[3].x
                                  + pB.x*v[4].x + pB.y*v[5].x + pB.z*v[6].x + pB.w*v[7].x;
                        acc[t].y += pA.x*v[0].y + pA.y*v[1].y + pA.z*v[2].y + pA.w*v[3].y
                                  + pB.x*v[4].y + pB.y*v[5].y + pB.z*v[6].y + pB.w*v[7].y;
                        acc[t].z += pA.x*v[0].z + pA.y*v[1].z + pA.z*v[2].z + pA.w*v[3].z
                                  + pB.x*v[4].z + pB.y*v[5].z + pB.z*v[6].z + pB.w*v[7].z;
                        acc[t].w += pA.x*v[0].w + pA.y*v[1].w + pA.z*v[2].w + pA.w*v[3].w
                                  + pB.x*v[4].w + pB.y*v[5].w + pB.z*v[6].w + pB.w*v[7].w;
                    }
                }
            }
            #pragma unroll
            for (int t = 0; t < TC; ++t) {
                if (t < nt) {
                    ((float4*)(out + (size_t)s_tok[t] * D))[tidx] = acc[t];
                }
            }
        }
        __syncthreads();   // next chunk rewrites s_uq/s_tok
    }
}

extern "C" void kernel_launch(void* const* d_in, const int* in_sizes, int n_in,
                              void* d_out, int out_size, void* d_ws, size_t ws_size,
                              hipStream_t stream) {
    const float* query    = (const float*)d_in[0];
    const int*   tids     = (const int*)  d_in[1];
    const float* skeys    = (const float*)d_in[2];
    const float* svals    = (const float*)d_in[3];
    const int*   stids    = (const int*)  d_in[4];
    const float* centroid = (const float*)d_in[5];
    float* out = (float*)d_out;
    const int n_tokens = in_sizes[1];

    int* cnt  = (int*)d_ws;             // [NB]
    int* list = cnt + NB;               // [NB*CAP]

    k_zero<<<1, 512, 0, stream>>>(cnt);
    k_build<<<(n_tokens + 255) / 256, 256, 0, stream>>>(tids, n_tokens, cnt, list);
    k_main<<<NB * 3, BT, 0, stream>>>(query, tids, skeys, svals, stids,
                                      centroid, out, cnt, list);
}